// Round 11
// baseline (559.840 us; speedup 1.0000x reference)
//
#include <hip/hip_runtime.h>

#define Nn 50000
#define Rr 16
#define Dd 64
#define Fin 128
#define Ee 100000
#define NE (Rr * Ee)     // 1600000
#define NBKT 782         // ceil(Nn/64) buckets (64 rows each)
#define CB 256           // count/place blocks
#define EPB (NE / CB)    // 6250 edges per block (16 blocks per relation)
#define SCTOT (NBKT * CB)  // 200192 count-matrix entries
#define SC_NB (SCTOT / 256)  // 782 scan blocks

typedef __attribute__((ext_vector_type(8))) short short8;
typedef __attribute__((ext_vector_type(4))) float f32x4;
typedef unsigned short ushort_t;

__device__ inline ushort_t f2bf(float x) {
  union { float f; unsigned u; } v; v.f = x;
  unsigned u = v.u;
  return (ushort_t)((u + 0x7FFFu + ((u >> 16) & 1u)) >> 16);  // RNE
}
__device__ inline float bf2f(ushort_t h) {
  union { unsigned u; float f; } v; v.u = ((unsigned)h) << 16; return v.f;
}

// ------- fused pre: MFMA init_gemm + convw + LDS-hist bucket count ---------
#define INIT_TILES 3125            // 50000/16
#define INIT_NB 782                // ceil(3125/4)
#define CONVW_NB 512               // 2*16*64*64 / 256
__global__ __launch_bounds__(256) void pre_k(const float* __restrict__ x,
                                             const float* __restrict__ ent,
                                             ushort_t* __restrict__ emb0,
                                             const float* __restrict__ rel,
                                             ushort_t* __restrict__ wbf,
                                             const int* __restrict__ erow,
                                             int* __restrict__ cnt) {
  __shared__ int lh[NBKT];
  int b = blockIdx.x;
  if (b < INIT_NB) {
    int wave = threadIdx.x >> 6, lane = threadIdx.x & 63;
    int nt = lane & 15, quad = lane >> 4;
    int tile = b * 4 + wave;
    if (tile >= INIT_TILES) return;
    const float* xr = x + ((long)tile * 16 + nt) * Fin + quad * 8;
    short8 afrag[4];
#pragma unroll
    for (int ks = 0; ks < 4; ++ks) {
      float4 p0 = *(const float4*)(xr + ks * 32);
      float4 p1 = *(const float4*)(xr + ks * 32 + 4);
      short8 a;
      a[0] = (short)f2bf(p0.x); a[1] = (short)f2bf(p0.y);
      a[2] = (short)f2bf(p0.z); a[3] = (short)f2bf(p0.w);
      a[4] = (short)f2bf(p1.x); a[5] = (short)f2bf(p1.y);
      a[6] = (short)f2bf(p1.z); a[7] = (short)f2bf(p1.w);
      afrag[ks] = a;
    }
    f32x4 acc[4];
#pragma unroll
    for (int dt = 0; dt < 4; ++dt) acc[dt] = (f32x4){0.f, 0.f, 0.f, 0.f};
#pragma unroll
    for (int ks = 0; ks < 4; ++ks) {
#pragma unroll
      for (int dt = 0; dt < 4; ++dt) {
        short8 bfr;
#pragma unroll
        for (int j = 0; j < 8; ++j)
          bfr[j] = (short)f2bf(ent[(unsigned)(ks * 32 + quad * 8 + j) * Dd + dt * 16 + nt]);
        acc[dt] = __builtin_amdgcn_mfma_f32_16x16x32_bf16(afrag[ks], bfr, acc[dt], 0, 0, 0);
      }
    }
#pragma unroll
    for (int dt = 0; dt < 4; ++dt)
#pragma unroll
      for (int reg = 0; reg < 4; ++reg) {
        int row = tile * 16 + quad * 4 + reg;
        emb0[(unsigned)row * Dd + dt * 16 + nt] = f2bf(acc[dt][reg]);
      }
  } else if (b < INIT_NB + CONVW_NB) {
    int i = (b - INIT_NB) * 256 + threadIdx.x;
    wbf[i] = f2bf(rel[i]);
  } else {
    int blk = b - INIT_NB - CONVW_NB;  // 0..CB-1
    int t = threadIdx.x;
    for (int i = t; i < NBKT; i += 256) lh[i] = 0;
    __syncthreads();
    int r = blk >> 4;
    long gbase = (long)r * Ee + (blk & 15) * EPB;
    for (int i = t; i < EPB; i += 256)
      atomicAdd(&lh[erow[gbase + i] >> 6], 1);  // LDS atomics only
    __syncthreads();
    for (int i = t; i < NBKT; i += 256) cnt[i * CB + blk] = lh[i];
  }
}

// ---------------- parallel scan over cnt[200192], bucket-major --------------
__global__ __launch_bounds__(256) void scan1_k(const int* __restrict__ cnt,
                                               int* __restrict__ bsum) {
  __shared__ int ls[256];
  int t = threadIdx.x;
  ls[t] = cnt[blockIdx.x * 256 + t];
  __syncthreads();
  for (int off = 128; off >= 1; off >>= 1) {
    if (t < off) ls[t] += ls[t + off];
    __syncthreads();
  }
  if (t == 0) bsum[blockIdx.x] = ls[0];
}

__global__ __launch_bounds__(1024) void scan2_k(int* __restrict__ bsum) {
  __shared__ int ls[1024];
  int t = threadIdx.x;
  int v = (t < SC_NB) ? bsum[t] : 0;
  ls[t] = v;
  __syncthreads();
  for (int off = 1; off < 1024; off <<= 1) {
    int x = (t >= off) ? ls[t - off] : 0;
    __syncthreads();
    ls[t] += x;
    __syncthreads();
  }
  if (t < SC_NB) bsum[t] = ls[t] - v;  // exclusive
}

__global__ __launch_bounds__(256) void scan3_k(int* __restrict__ cnt,
                                               const int* __restrict__ bsum,
                                               int* __restrict__ cbase,
                                               int* __restrict__ offs) {
  __shared__ int ls[256];
  int t = threadIdx.x, i = blockIdx.x * 256 + t;
  int v = cnt[i];
  ls[t] = v;
  __syncthreads();
  for (int off = 1; off < 256; off <<= 1) {
    int x = (t >= off) ? ls[t - off] : 0;
    __syncthreads();
    ls[t] += x;
    __syncthreads();
  }
  int excl = ls[t] - v + bsum[blockIdx.x];
  cnt[i] = excl;
  if (t == 0) cbase[blockIdx.x] = excl;
  if (i == SCTOT - 1) { cbase[NBKT] = NE; offs[Nn] = NE; }
}

// ------- place: edges -> bucket-grouped ebkt, LDS cursors, block-private ----
__global__ __launch_bounds__(256) void place_k(const int* __restrict__ erow,
                                               const int* __restrict__ ecol,
                                               const float* __restrict__ ev,
                                               const int* __restrict__ base,
                                               uint2* __restrict__ ebkt) {
  __shared__ int lofs[NBKT];
  int blk = blockIdx.x, t = threadIdx.x;
  for (int i = t; i < NBKT; i += 256) lofs[i] = base[i * CB + blk];
  __syncthreads();
  int r = blk >> 4;
  long gbase = (long)r * Ee + (blk & 15) * EPB;
  for (int i = t; i < EPB; i += 256) {
    long idx = gbase + i;
    int row = erow[idx];
    int pos = atomicAdd(&lofs[row >> 6], 1);
    unsigned vb = f2bf(ev[idx]);
    ebkt[pos] = make_uint2(((unsigned)(row & 63) << 4) | (unsigned)r,
                           (vb << 16) | (unsigned)ecol[idx]);
  }
}

// ------- cluster sort: 64-row cluster -> row-contiguous ed2 + offs ---------
__global__ __launch_bounds__(256) void csort_k(const uint2* __restrict__ ebkt,
                                               const int* __restrict__ cbase,
                                               uint2* __restrict__ ed2,
                                               int* __restrict__ offs) {
  __shared__ int lcnt[64], lstart[64], lcur[64];
  int c = blockIdx.x, t = threadIdx.x;
  int s = cbase[c], e = cbase[c + 1];
  if (t < 64) lcnt[t] = 0;
  __syncthreads();
  for (int i = s + t; i < e; i += 256) atomicAdd(&lcnt[ebkt[i].x >> 4], 1);
  __syncthreads();
  if (t == 0) {
    int run = 0;
    for (int rl = 0; rl < 64; ++rl) {
      int cc = lcnt[rl];
      lstart[rl] = run; lcur[rl] = run; run += cc;
    }
  }
  __syncthreads();
  int nrow = Nn - c * 64; if (nrow > 64) nrow = 64;
  if (t < nrow) offs[c * 64 + t] = s + lstart[t];
  for (int i = s + t; i < e; i += 256) {
    uint2 q = ebkt[i];
    int pos = s + atomicAdd(&lcur[q.x >> 4], 1);
    ed2[pos] = make_uint2(q.x & 15u, q.y);
  }
}

// ------- fused layer: gather (selector MFMA) + transform + epilogue ---------
// Block = 4 rows (wave per row). Phase 1 = gather6 (Z row in C-layout regs).
// Phase 1.5: Z rows -> LDS bf16, k-major (k=rel*64+d), pitch 1028 (<=2-way
// conflicts = free). Phase 2: out[4][64] = Zl[4x1024] @ Wcat[64x1024]^T,
// K split across 4 waves (A rows >=4 garbage, their C rows unused), partials
// reduced via 4KB LDS aliased onto the dead staging buffer. Z never hits HBM.
#define PITCH 40   // staging pitch (shorts)
#define ZP 1028    // Zl pitch (shorts)
__global__ __launch_bounds__(256) void flayer_k(const ushort_t* __restrict__ emb,
                                                const ushort_t* __restrict__ wl,
                                                const int* __restrict__ offs,
                                                const uint2* __restrict__ ed2,
                                                ushort_t* __restrict__ embout,
                                                float* __restrict__ finout,
                                                int fin) {
  __shared__ ushort_t stg[4][Dd * PITCH];  // 20480 B, wave-private staging
  __shared__ ushort_t Zl[4 * ZP];          // 8224 B
  float* red = (float*)stg;                // alias: safe after phase-1.5 barrier
  const int wave = threadIdx.x >> 6, lane = threadIdx.x & 63;
  const int nt = lane & 15, quad = lane >> 4;
  const int row = blockIdx.x * 4 + wave;   // grid = Nn/4 exact
  ushort_t* lw = stg[wave];

  // ---- phase 1: gather ----
  int off_l = (lane < 2) ? offs[row + lane] : 0;
  const int base = __shfl(off_l, 0, 64);
  const int len  = __shfl(off_l, 1, 64) - base;

  f32x4 acc[4];
#pragma unroll
  for (int dt = 0; dt < 4; ++dt) acc[dt] = (f32x4){0.f, 0.f, 0.f, 0.f};

  for (int c = 0; c < len; c += 32) {
    int p = c + (lane & 31);
    uint2 myed = (p < len) ? ed2[base + p] : make_uint2(0u, 0u);  // pad: val=0
#pragma unroll
    for (int h = 0; h < 2; ++h) {
      ushort_t y[16];
#pragma unroll
      for (int j = 0; j < 16; ++j) {
        unsigned qy = (unsigned)__shfl((int)myed.y, h * 16 + j, 64);
        y[j] = emb[(qy & 0xFFFFu) * 64u + lane];
      }
#pragma unroll
      for (int g = 0; g < 4; ++g) {
        unsigned lo = (unsigned)y[g * 4]     | ((unsigned)y[g * 4 + 1] << 16);
        unsigned hi = (unsigned)y[g * 4 + 2] | ((unsigned)y[g * 4 + 3] << 16);
        *(uint2*)(lw + lane * PITCH + h * 16 + g * 4) = make_uint2(lo, hi);
      }
    }
    short8 afr;
#pragma unroll
    for (int j = 0; j < 8; ++j) {
      int slot = quad * 8 + j;
      unsigned qx = (unsigned)__shfl((int)myed.x, slot, 64);
      unsigned qy = (unsigned)__shfl((int)myed.y, slot, 64);
      afr[j] = ((int)qx == nt) ? (short)(qy >> 16) : (short)0;
    }
#pragma unroll
    for (int dt = 0; dt < 4; ++dt) {
      short8 bfr = *(const short8*)(lw + (dt * 16 + nt) * PITCH + quad * 8);
      acc[dt] = __builtin_amdgcn_mfma_f32_16x16x32_bf16(afr, bfr, acc[dt], 0, 0, 0);
    }
  }

  // ---- phase 1.5: Z row -> Zl (bf16, k = rel*64 + d) ----
  ushort_t* zr = Zl + wave * ZP;
#pragma unroll
  for (int dt = 0; dt < 4; ++dt)
#pragma unroll
    for (int reg = 0; reg < 4; ++reg)
      zr[(quad * 4 + reg) * 64 + dt * 16 + nt] = f2bf(acc[dt][reg]);
  __syncthreads();  // all waves done with staging + Zl complete

  // ---- phase 2: transform, K-chunk per wave ----
  f32x4 cacc[4];
#pragma unroll
  for (int dt = 0; dt < 4; ++dt) cacc[dt] = (f32x4){0.f, 0.f, 0.f, 0.f};
  const int kbase = wave * 256;
#pragma unroll
  for (int ks = 0; ks < 8; ++ks) {
    int k0 = kbase + ks * 32 + quad * 8;
    short8 a = *(const short8*)(Zl + (nt & 3) * ZP + k0);  // A[m=nt][k], rows>=4 dup
    int r = k0 >> 6, d0 = k0 & 63;
    const ushort_t* wb = wl + (unsigned)r * 4096u + d0;
#pragma unroll
    for (int dt = 0; dt < 4; ++dt) {
      short8 b = *(const short8*)(wb + (unsigned)(dt * 16 + nt) * 64u);
      cacc[dt] = __builtin_amdgcn_mfma_f32_16x16x32_bf16(a, b, cacc[dt], 0, 0, 0);
    }
  }

  // ---- reduce partials across waves (red aliases dead staging) ----
  if (quad == 0) {
#pragma unroll
    for (int dt = 0; dt < 4; ++dt)
#pragma unroll
      for (int reg = 0; reg < 4; ++reg)
        red[(wave * 4 + reg) * 64 + dt * 16 + nt] = cacc[dt][reg];
  }
  __syncthreads();
  float s = red[(0 * 4 + wave) * 64 + lane] + red[(1 * 4 + wave) * 64 + lane] +
            red[(2 * 4 + wave) * 64 + lane] + red[(3 * 4 + wave) * 64 + lane];

  // ---- epilogue ----
  if (!fin) {
    embout[(unsigned)row * 64u + lane] = f2bf(fmaxf(s, 0.f));
  } else {
    float v = fmaxf(s, 0.f);
    float ss = v * v;
#pragma unroll
    for (int off = 32; off >= 1; off >>= 1) ss += __shfl_xor(ss, off, 64);
    finout[(unsigned)row * 64u + lane] = v / fmaxf(sqrtf(ss), 1e-12f);
  }
}

extern "C" void kernel_launch(void* const* d_in, const int* in_sizes, int n_in,
                              void* d_out, int out_size, void* d_ws, size_t ws_size,
                              hipStream_t stream) {
  const float* x   = (const float*)d_in[0];
  const float* ent = (const float*)d_in[1];
  const float* rel = (const float*)d_in[2];
  const int* erow  = (const int*)d_in[3];
  const int* ecol  = (const int*)d_in[4];
  const float* ev  = (const float*)d_in[5];
  float* out = (float*)d_out;

  char* p = (char*)d_ws;
  ushort_t* emb_a = (ushort_t*)p;  p += (size_t)Nn * Dd * 2;           // 6.4 MB
  ushort_t* emb_b = (ushort_t*)p;  p += (size_t)Nn * Dd * 2;           // 6.4 MB
  ushort_t* wbf   = (ushort_t*)p;  p += (size_t)2 * Rr * Dd * Dd * 2;  // 256 KB
  uint2* ebkt     = (uint2*)p;     p += (size_t)NE * 8;                // 12.8 MB
  uint2* ed2      = (uint2*)p;     p += (size_t)NE * 8;                // 12.8 MB
  int* cnt        = (int*)p;       p += (size_t)SCTOT * 4;             // 0.8 MB
  int* bsum       = (int*)p;       p += (size_t)(SC_NB + 8) * 4;
  int* cbase      = (int*)p;       p += (size_t)(NBKT + 8) * 4;
  int* offs       = (int*)p;       p += (size_t)(Nn + 8) * 4;          // 0.2 MB

  pre_k<<<INIT_NB + CONVW_NB + CB, 256, 0, stream>>>(
      x, ent, emb_a, rel, wbf, erow, cnt);
  scan1_k<<<SC_NB, 256, 0, stream>>>(cnt, bsum);
  scan2_k<<<1, 1024, 0, stream>>>(bsum);
  scan3_k<<<SC_NB, 256, 0, stream>>>(cnt, bsum, cbase, offs);
  place_k<<<CB, 256, 0, stream>>>(erow, ecol, ev, cnt, ebkt);
  csort_k<<<NBKT, 256, 0, stream>>>(ebkt, cbase, ed2, offs);

  // layer 1: emb_a -> emb_b (relu'd bf16)
  flayer_k<<<Nn / 4, 256, 0, stream>>>(emb_a, wbf, offs, ed2, emb_b, nullptr, 0);
  // layer 2: emb_b -> out (relu + L2 normalize, f32)
  flayer_k<<<Nn / 4, 256, 0, stream>>>(emb_b, wbf + (size_t)Rr * Dd * Dd, offs,
                                       ed2, nullptr, out, 1);
}

// Round 12
// 425.442 us; speedup vs baseline: 1.3159x; 1.3159x over previous
//
#include <hip/hip_runtime.h>

#define Nn 50000
#define Rr 16
#define Dd 64
#define Fin 128
#define Ee 100000
#define NE (Rr * Ee)     // 1600000
#define NBKT 782         // ceil(Nn/64) buckets (64 rows each)
#define CB 256           // count/place blocks
#define EPB (NE / CB)    // 6250 edges per block (16 blocks per relation)
#define SCTOT (NBKT * CB)  // 200192 count-matrix entries
#define SC_NB (SCTOT / 256)  // 782 scan blocks
#define NTILE (Nn / 16)  // 3125

typedef __attribute__((ext_vector_type(8))) short short8;
typedef __attribute__((ext_vector_type(4))) float f32x4;
typedef unsigned short ushort_t;

__device__ inline ushort_t f2bf(float x) {
  union { float f; unsigned u; } v; v.f = x;
  unsigned u = v.u;
  return (ushort_t)((u + 0x7FFFu + ((u >> 16) & 1u)) >> 16);  // RNE
}
__device__ inline float bf2f(ushort_t h) {
  union { unsigned u; float f; } v; v.u = ((unsigned)h) << 16; return v.f;
}

// ------- fused pre: MFMA init_gemm + convw + LDS-hist bucket count ---------
#define INIT_TILES 3125            // 50000/16
#define INIT_NB 782                // ceil(3125/4)
#define CONVW_NB 512               // 2*16*64*64 / 256
__global__ __launch_bounds__(256) void pre_k(const float* __restrict__ x,
                                             const float* __restrict__ ent,
                                             ushort_t* __restrict__ emb0,
                                             const float* __restrict__ rel,
                                             ushort_t* __restrict__ wbf,
                                             const int* __restrict__ erow,
                                             int* __restrict__ cnt) {
  __shared__ int lh[NBKT];
  int b = blockIdx.x;
  if (b < INIT_NB) {
    int wave = threadIdx.x >> 6, lane = threadIdx.x & 63;
    int nt = lane & 15, quad = lane >> 4;
    int tile = b * 4 + wave;
    if (tile >= INIT_TILES) return;
    const float* xr = x + ((long)tile * 16 + nt) * Fin + quad * 8;
    short8 afrag[4];
#pragma unroll
    for (int ks = 0; ks < 4; ++ks) {
      float4 p0 = *(const float4*)(xr + ks * 32);
      float4 p1 = *(const float4*)(xr + ks * 32 + 4);
      short8 a;
      a[0] = (short)f2bf(p0.x); a[1] = (short)f2bf(p0.y);
      a[2] = (short)f2bf(p0.z); a[3] = (short)f2bf(p0.w);
      a[4] = (short)f2bf(p1.x); a[5] = (short)f2bf(p1.y);
      a[6] = (short)f2bf(p1.z); a[7] = (short)f2bf(p1.w);
      afrag[ks] = a;
    }
    f32x4 acc[4];
#pragma unroll
    for (int dt = 0; dt < 4; ++dt) acc[dt] = (f32x4){0.f, 0.f, 0.f, 0.f};
#pragma unroll
    for (int ks = 0; ks < 4; ++ks) {
#pragma unroll
      for (int dt = 0; dt < 4; ++dt) {
        short8 bfr;
#pragma unroll
        for (int j = 0; j < 8; ++j)
          bfr[j] = (short)f2bf(ent[(unsigned)(ks * 32 + quad * 8 + j) * Dd + dt * 16 + nt]);
        acc[dt] = __builtin_amdgcn_mfma_f32_16x16x32_bf16(afrag[ks], bfr, acc[dt], 0, 0, 0);
      }
    }
#pragma unroll
    for (int dt = 0; dt < 4; ++dt)
#pragma unroll
      for (int reg = 0; reg < 4; ++reg) {
        int row = tile * 16 + quad * 4 + reg;
        emb0[(unsigned)row * Dd + dt * 16 + nt] = f2bf(acc[dt][reg]);
      }
  } else if (b < INIT_NB + CONVW_NB) {
    int i = (b - INIT_NB) * 256 + threadIdx.x;
    wbf[i] = f2bf(rel[i]);
  } else {
    int blk = b - INIT_NB - CONVW_NB;  // 0..CB-1
    int t = threadIdx.x;
    for (int i = t; i < NBKT; i += 256) lh[i] = 0;
    __syncthreads();
    int r = blk >> 4;
    long gbase = (long)r * Ee + (blk & 15) * EPB;
    for (int i = t; i < EPB; i += 256)
      atomicAdd(&lh[erow[gbase + i] >> 6], 1);  // LDS atomics only
    __syncthreads();
    for (int i = t; i < NBKT; i += 256) cnt[i * CB + blk] = lh[i];
  }
}

// ---------------- parallel scan over cnt[200192], bucket-major --------------
__global__ __launch_bounds__(256) void scan1_k(const int* __restrict__ cnt,
                                               int* __restrict__ bsum) {
  __shared__ int ls[256];
  int t = threadIdx.x;
  ls[t] = cnt[blockIdx.x * 256 + t];
  __syncthreads();
  for (int off = 128; off >= 1; off >>= 1) {
    if (t < off) ls[t] += ls[t + off];
    __syncthreads();
  }
  if (t == 0) bsum[blockIdx.x] = ls[0];
}

__global__ __launch_bounds__(1024) void scan2_k(int* __restrict__ bsum) {
  __shared__ int ls[1024];
  int t = threadIdx.x;
  int v = (t < SC_NB) ? bsum[t] : 0;
  ls[t] = v;
  __syncthreads();
  for (int off = 1; off < 1024; off <<= 1) {
    int x = (t >= off) ? ls[t - off] : 0;
    __syncthreads();
    ls[t] += x;
    __syncthreads();
  }
  if (t < SC_NB) bsum[t] = ls[t] - v;  // exclusive
}

__global__ __launch_bounds__(256) void scan3_k(int* __restrict__ cnt,
                                               const int* __restrict__ bsum,
                                               int* __restrict__ cbase,
                                               int* __restrict__ offs) {
  __shared__ int ls[256];
  int t = threadIdx.x, i = blockIdx.x * 256 + t;
  int v = cnt[i];
  ls[t] = v;
  __syncthreads();
  for (int off = 1; off < 256; off <<= 1) {
    int x = (t >= off) ? ls[t - off] : 0;
    __syncthreads();
    ls[t] += x;
    __syncthreads();
  }
  int excl = ls[t] - v + bsum[blockIdx.x];
  cnt[i] = excl;
  if (t == 0) cbase[blockIdx.x] = excl;
  if (i == SCTOT - 1) { cbase[NBKT] = NE; offs[Nn] = NE; }
}

// ------- place: edges -> bucket-grouped ebkt, LDS cursors, block-private ----
__global__ __launch_bounds__(256) void place_k(const int* __restrict__ erow,
                                               const int* __restrict__ ecol,
                                               const float* __restrict__ ev,
                                               const int* __restrict__ base,
                                               uint2* __restrict__ ebkt) {
  __shared__ int lofs[NBKT];
  int blk = blockIdx.x, t = threadIdx.x;
  for (int i = t; i < NBKT; i += 256) lofs[i] = base[i * CB + blk];
  __syncthreads();
  int r = blk >> 4;
  long gbase = (long)r * Ee + (blk & 15) * EPB;
  for (int i = t; i < EPB; i += 256) {
    long idx = gbase + i;
    int row = erow[idx];
    int pos = atomicAdd(&lofs[row >> 6], 1);
    unsigned vb = f2bf(ev[idx]);
    ebkt[pos] = make_uint2(((unsigned)(row & 63) << 4) | (unsigned)r,
                           (vb << 16) | (unsigned)ecol[idx]);
  }
}

// ------- cluster sort: 64-row cluster -> row-contiguous ed2 + offs ---------
__global__ __launch_bounds__(256) void csort_k(const uint2* __restrict__ ebkt,
                                               const int* __restrict__ cbase,
                                               uint2* __restrict__ ed2,
                                               int* __restrict__ offs) {
  __shared__ int lcnt[64], lstart[64], lcur[64];
  int c = blockIdx.x, t = threadIdx.x;
  int s = cbase[c], e = cbase[c + 1];
  if (t < 64) lcnt[t] = 0;
  __syncthreads();
  for (int i = s + t; i < e; i += 256) atomicAdd(&lcnt[ebkt[i].x >> 4], 1);
  __syncthreads();
  if (t == 0) {
    int run = 0;
    for (int rl = 0; rl < 64; ++rl) {
      int cc = lcnt[rl];
      lstart[rl] = run; lcur[rl] = run; run += cc;
    }
  }
  __syncthreads();
  int nrow = Nn - c * 64; if (nrow > 64) nrow = 64;
  if (t < nrow) offs[c * 64 + t] = s + lstart[t];
  for (int i = s + t; i < e; i += 256) {
    uint2 q = ebkt[i];
    int pos = s + atomicAdd(&lcur[q.x >> 4], 1);
    ed2[pos] = make_uint2(q.x & 15u, q.y);
  }
}

// ---------------- gather6: lane-parallel prefetch + rel-selector MFMA -------
#define PITCH 40  // shorts; 80B rows: b64 writes & b128 reads at bank floor
__global__ __launch_bounds__(256) void gather6_k(const ushort_t* __restrict__ emb,
                                                 const int* __restrict__ offs,
                                                 const uint2* __restrict__ ed2,
                                                 ushort_t* __restrict__ Z) {
  __shared__ ushort_t lds[4][Dd * PITCH];  // 4 x 5120B, wave-private
  const int wave = threadIdx.x >> 6, lane = threadIdx.x & 63;
  const int nt = lane & 15, quad = lane >> 4;
  const int row = blockIdx.x * 4 + wave;
  if (row >= Nn) return;
  ushort_t* lw = lds[wave];

  int off_l = (lane < 2) ? offs[row + lane] : 0;
  const int base = __shfl(off_l, 0, 64);
  const int len  = __shfl(off_l, 1, 64) - base;

  f32x4 acc[4];
#pragma unroll
  for (int dt = 0; dt < 4; ++dt) acc[dt] = (f32x4){0.f, 0.f, 0.f, 0.f};

  for (int c = 0; c < len; c += 32) {
    int p = c + (lane & 31);
    uint2 myed = (p < len) ? ed2[base + p] : make_uint2(0u, 0u);  // pad: val=0
#pragma unroll
    for (int h = 0; h < 2; ++h) {
      ushort_t y[16];
#pragma unroll
      for (int j = 0; j < 16; ++j) {
        unsigned qy = (unsigned)__shfl((int)myed.y, h * 16 + j, 64);
        y[j] = emb[(qy & 0xFFFFu) * 64u + lane];
      }
#pragma unroll
      for (int g = 0; g < 4; ++g) {
        unsigned lo = (unsigned)y[g * 4]     | ((unsigned)y[g * 4 + 1] << 16);
        unsigned hi = (unsigned)y[g * 4 + 2] | ((unsigned)y[g * 4 + 3] << 16);
        *(uint2*)(lw + lane * PITCH + h * 16 + g * 4) = make_uint2(lo, hi);
      }
    }
    short8 afr;
#pragma unroll
    for (int j = 0; j < 8; ++j) {
      int slot = quad * 8 + j;
      unsigned qx = (unsigned)__shfl((int)myed.x, slot, 64);
      unsigned qy = (unsigned)__shfl((int)myed.y, slot, 64);
      afr[j] = ((int)qx == nt) ? (short)(qy >> 16) : (short)0;
    }
#pragma unroll
    for (int dt = 0; dt < 4; ++dt) {
      short8 bfr = *(const short8*)(lw + (dt * 16 + nt) * PITCH + quad * 8);
      acc[dt] = __builtin_amdgcn_mfma_f32_16x16x32_bf16(afr, bfr, acc[dt], 0, 0, 0);
    }
  }

  // D[m=quad*4+reg][n=dt*16+nt]: m=rel, n=d -> Z[row][rel][d]
  ushort_t* zrow = Z + (size_t)row * (Rr * Dd);
#pragma unroll
  for (int dt = 0; dt < 4; ++dt)
#pragma unroll
    for (int reg = 0; reg < 4; ++reg)
      zrow[(quad * 4 + reg) * Dd + dt * 16 + nt] = f2bf(acc[dt][reg]);
}

// ------- zgemm split-K: 2 waves per 16-row tile (rels 0-7 / 8-15) ----------
// Grid 1563 blocks x 4 waves (2 tiles/block) -> 2x resident waves vs R10,
// half the dependent-load chain per wave. Partials reduced via 8KB LDS
// (b128 float stores, 2-way bank pattern = free); epilogue in kh==0 wave.
__global__ __launch_bounds__(256) void zgemm_k(const ushort_t* __restrict__ Z,
                                               const ushort_t* __restrict__ wl,
                                               ushort_t* __restrict__ embout,
                                               float* __restrict__ finout,
                                               int fin) {
  __shared__ float red[2][64 * 16];  // [tile_local][lane*16+idx] = 8KB
  int wave = threadIdx.x >> 6, lane = threadIdx.x & 63;
  int nt = lane & 15, quad = lane >> 4;
  int tl = wave >> 1, kh = wave & 1;
  int tile = blockIdx.x * 2 + tl;
  if (tile >= NTILE) tile = NTILE - 1;  // dup work; identical values written

  const ushort_t* za = Z + (size_t)(tile * 16 + nt) * (Rr * Dd) + quad * 8;
  f32x4 acc[4];
#pragma unroll
  for (int dt = 0; dt < 4; ++dt) acc[dt] = (f32x4){0.f, 0.f, 0.f, 0.f};

#pragma unroll 2
  for (int r8 = 0; r8 < 8; ++r8) {
    int r = kh * 8 + r8;
    short8 a0 = *(const short8*)(za + r * Dd);
    short8 a1 = *(const short8*)(za + r * Dd + 32);
#pragma unroll
    for (int dt = 0; dt < 4; ++dt) {
      const ushort_t* bp = wl + ((unsigned)r * Dd + dt * 16 + nt) * Dd + quad * 8;
      short8 b0 = *(const short8*)(bp);
      short8 b1 = *(const short8*)(bp + 32);
      acc[dt] = __builtin_amdgcn_mfma_f32_16x16x32_bf16(a0, b0, acc[dt], 0, 0, 0);
      acc[dt] = __builtin_amdgcn_mfma_f32_16x16x32_bf16(a1, b1, acc[dt], 0, 0, 0);
    }
  }

  // kh==1 waves deposit partials; kh==0 waves combine + epilogue
  if (kh == 1) {
    float* rp = red[tl] + lane * 16;
#pragma unroll
    for (int dt = 0; dt < 4; ++dt)
      *(f32x4*)(rp + dt * 4) = acc[dt];
  }
  __syncthreads();
  if (kh == 1) return;
  {
    const float* rp = red[tl] + lane * 16;
#pragma unroll
    for (int dt = 0; dt < 4; ++dt) {
      f32x4 o = *(const f32x4*)(rp + dt * 4);
#pragma unroll
      for (int reg = 0; reg < 4; ++reg) acc[dt][reg] += o[reg];
    }
  }

  if (!fin) {
#pragma unroll
    for (int dt = 0; dt < 4; ++dt)
#pragma unroll
      for (int reg = 0; reg < 4; ++reg) {
        int row = tile * 16 + quad * 4 + reg;
        embout[(unsigned)row * 64u + dt * 16 + nt] = f2bf(fmaxf(acc[dt][reg], 0.f));
      }
  } else {
    float v[4][4];
#pragma unroll
    for (int dt = 0; dt < 4; ++dt)
#pragma unroll
      for (int reg = 0; reg < 4; ++reg) v[dt][reg] = fmaxf(acc[dt][reg], 0.f);
#pragma unroll
    for (int reg = 0; reg < 4; ++reg) {
      float ss = 0.f;
#pragma unroll
      for (int dt = 0; dt < 4; ++dt) ss = fmaf(v[dt][reg], v[dt][reg], ss);
#pragma unroll
      for (int off = 8; off >= 1; off >>= 1)
        ss += __shfl_xor(ss, off, 64);  // reduce over nt (quad bits preserved)
      float sc = 1.f / fmaxf(sqrtf(ss), 1e-12f);
      int row = tile * 16 + quad * 4 + reg;
#pragma unroll
      for (int dt = 0; dt < 4; ++dt)
        finout[(unsigned)row * 64u + dt * 16 + nt] = v[dt][reg] * sc;
    }
  }
}

extern "C" void kernel_launch(void* const* d_in, const int* in_sizes, int n_in,
                              void* d_out, int out_size, void* d_ws, size_t ws_size,
                              hipStream_t stream) {
  const float* x   = (const float*)d_in[0];
  const float* ent = (const float*)d_in[1];
  const float* rel = (const float*)d_in[2];
  const int* erow  = (const int*)d_in[3];
  const int* ecol  = (const int*)d_in[4];
  const float* ev  = (const float*)d_in[5];
  float* out = (float*)d_out;

  char* p = (char*)d_ws;
  ushort_t* emb_a = (ushort_t*)p;  p += (size_t)Nn * Dd * 2;           // 6.4 MB
  ushort_t* emb_b = (ushort_t*)p;  p += (size_t)Nn * Dd * 2;           // 6.4 MB
  ushort_t* wbf   = (ushort_t*)p;  p += (size_t)2 * Rr * Dd * Dd * 2;  // 256 KB
  ushort_t* Z     = (ushort_t*)p;  p += (size_t)Nn * Rr * Dd * 2;      // 102.4 MB
  uint2* ebkt     = (uint2*)p;     p += (size_t)NE * 8;                // 12.8 MB
  uint2* ed2      = (uint2*)p;     p += (size_t)NE * 8;                // 12.8 MB
  int* cnt        = (int*)p;       p += (size_t)SCTOT * 4;             // 0.8 MB
  int* bsum       = (int*)p;       p += (size_t)(SC_NB + 8) * 4;
  int* cbase      = (int*)p;       p += (size_t)(NBKT + 8) * 4;
  int* offs       = (int*)p;       p += (size_t)(Nn + 8) * 4;          // 0.2 MB

  pre_k<<<INIT_NB + CONVW_NB + CB, 256, 0, stream>>>(
      x, ent, emb_a, rel, wbf, erow, cnt);
  scan1_k<<<SC_NB, 256, 0, stream>>>(cnt, bsum);
  scan2_k<<<1, 1024, 0, stream>>>(bsum);
  scan3_k<<<SC_NB, 256, 0, stream>>>(cnt, bsum, cbase, offs);
  place_k<<<CB, 256, 0, stream>>>(erow, ecol, ev, cnt, ebkt);
  csort_k<<<NBKT, 256, 0, stream>>>(ebkt, cbase, ed2, offs);

  // layer 1
  gather6_k<<<(Nn + 3) / 4, 256, 0, stream>>>(emb_a, offs, ed2, Z);
  zgemm_k<<<(NTILE + 1) / 2, 256, 0, stream>>>(Z, wbf, emb_b, nullptr, 0);
  // layer 2 (+ relu + L2 normalize fused)
  gather6_k<<<(Nn + 3) / 4, 256, 0, stream>>>(emb_b, offs, ed2, Z);
  zgemm_k<<<(NTILE + 1) / 2, 256, 0, stream>>>(Z, wbf + (size_t)Rr * Dd * Dd,
                                               nullptr, out, 1);
}